// Round 1
// baseline (330.789 us; speedup 1.0000x reference)
//
#include <hip/hip_runtime.h>

constexpr int C  = 256;
constexpr int H  = 224;
constexpr int W  = 224;
constexpr int HW = H * W;               // 50176
constexpr int PIX = 64;                 // pixels per block
constexpr int THREADS = 256;
constexpr int TILES_PER_B = HW / PIX;   // 784 (exact)
constexpr int BATCH = 16;

__global__ __launch_bounds__(THREADS, 2)
void fused_sigmoid_border_scale(const float* __restrict__ x,
                                const float* __restrict__ wv,
                                const float* __restrict__ bv,
                                float* __restrict__ out)
{
    __shared__ float tile[C * PIX];      // 64 KB: layout [c][p], stride 64
    __shared__ float partial[4 * PIX];   // 1 KB
    __shared__ float comb[PIX];          // 256 B

    const int t   = threadIdx.x;
    const int blk = blockIdx.x;
    const int b   = blk / TILES_PER_B;
    const int hw0 = (blk - b * TILES_PER_B) * PIX;

    const float* xb = x   + (size_t)b * C * HW + hw0;
    float*       ob = out + (size_t)b * C * HW + hw0;

    const int q  = t & 15;   // float4 column within a 64-pixel row (q*4 .. q*4+3)
    const int c0 = t >> 4;   // base channel offset (0..15)

    // ---- stage: global -> LDS, fully coalesced float4 ----
    #pragma unroll
    for (int k = 0; k < 16; ++k) {
        const int c = k * 16 + c0;
        float4 v = *reinterpret_cast<const float4*>(xb + (size_t)c * HW + q * 4);
        *reinterpret_cast<float4*>(&tile[c * PIX + q * 4]) = v;
    }
    __syncthreads();

    // ---- channel dot-product: 4 c-groups x 64 pixels ----
    {
        const int cg = t >> 6;        // wave-uniform
        const int p  = t & 63;
        const float* wp = wv + cg * 64;
        const float* tp = tile + (cg * 64) * PIX + p;
        float s = 0.f;
        #pragma unroll
        for (int k = 0; k < 64; ++k)
            s += tp[k * PIX] * wp[k];
        partial[cg * PIX + p] = s;
    }
    __syncthreads();

    if (t < PIX) {
        float s = partial[t] + partial[PIX + t] + partial[2 * PIX + t]
                + partial[3 * PIX + t] + bv[0];
        float att = 1.0f / (1.0f + expf(-s));
        const int hw = hw0 + t;
        const int h  = hw / W;
        const int w  = hw - h * W;
        const bool border = (h == 0) | (h == H - 1) | (w == 0) | (w == W - 1);
        comb[t] = att * (border ? 2.0f : 1.0f);
    }
    __syncthreads();

    // ---- scale & write: LDS -> global, coalesced float4 ----
    const float4 m = *reinterpret_cast<const float4*>(&comb[q * 4]);
    #pragma unroll
    for (int k = 0; k < 16; ++k) {
        const int c = k * 16 + c0;
        float4 v = *reinterpret_cast<const float4*>(&tile[c * PIX + q * 4]);
        v.x *= m.x; v.y *= m.y; v.z *= m.z; v.w *= m.w;
        *reinterpret_cast<float4*>(ob + (size_t)c * HW + q * 4) = v;
    }
}

extern "C" void kernel_launch(void* const* d_in, const int* in_sizes, int n_in,
                              void* d_out, int out_size, void* d_ws, size_t ws_size,
                              hipStream_t stream) {
    const float* x  = (const float*)d_in[0];
    const float* wv = (const float*)d_in[1];
    const float* bv = (const float*)d_in[2];
    float* out = (float*)d_out;

    dim3 grid(BATCH * TILES_PER_B);   // 12544 blocks
    fused_sigmoid_border_scale<<<grid, THREADS, 0, stream>>>(x, wv, bv, out);
}

// Round 3
// 314.606 us; speedup vs baseline: 1.0514x; 1.0514x over previous
//
#include <hip/hip_runtime.h>

constexpr int C  = 256;
constexpr int H  = 224;
constexpr int W  = 224;
constexpr int HW = H * W;               // 50176
constexpr int PIX = 64;                 // pixels per block
constexpr int THREADS = 256;
constexpr int TILES_PER_B = HW / PIX;   // 784 (exact)
constexpr int BATCH = 16;

typedef float f32x4 __attribute__((ext_vector_type(4)));

__global__ __launch_bounds__(THREADS, 4)
void fused_sigmoid_border_scale(const float* __restrict__ x,
                                const float* __restrict__ wv,
                                const float* __restrict__ bv,
                                float* __restrict__ out)
{
    __shared__ f32x4 pw[4][16];    // per-wave partial sums (1 KB)
    __shared__ float comb[PIX];    // 256 B

    const int t   = threadIdx.x;
    const int blk = blockIdx.x;
    const int b   = blk / TILES_PER_B;
    const int hw0 = (blk - b * TILES_PER_B) * PIX;

    const float* xb = x   + (size_t)b * C * HW + hw0;
    float*       ob = out + (size_t)b * C * HW + hw0;

    const int q    = t & 15;   // float4 column (pixels q*4..q*4+3)
    const int c0   = t >> 4;   // channel subgroup 0..15
    const int wave = t >> 6;

    // ---- load tile into registers: 16 coalesced 16B loads per thread ----
    f32x4 v[16];
    #pragma unroll
    for (int k = 0; k < 16; ++k) {
        const int c = k * 16 + c0;
        v[k] = __builtin_nontemporal_load(
            reinterpret_cast<const f32x4*>(xb + (size_t)c * HW + q * 4));
    }

    // ---- per-thread partial dot over this thread's 16 channels ----
    f32x4 acc = (f32x4)(0.f);
    #pragma unroll
    for (int k = 0; k < 16; ++k) {
        const float wk = wv[k * 16 + c0];
        acc.x = fmaf(v[k].x, wk, acc.x);
        acc.y = fmaf(v[k].y, wk, acc.y);
        acc.z = fmaf(v[k].z, wk, acc.z);
        acc.w = fmaf(v[k].w, wk, acc.w);
    }

    // ---- intra-wave reduce across the 4 c0-subgroups (lanes q, q+16, q+32, q+48) ----
    #pragma unroll
    for (int m = 16; m <= 32; m <<= 1) {
        acc.x += __shfl_xor(acc.x, m);
        acc.y += __shfl_xor(acc.y, m);
        acc.z += __shfl_xor(acc.z, m);
        acc.w += __shfl_xor(acc.w, m);
    }
    if ((t & 63) < 16) pw[wave][q] = acc;   // one f32x4 per q per wave
    __syncthreads();

    // ---- cross-wave combine + sigmoid + border (64 threads) ----
    if (t < PIX) {
        const int qq = t >> 2, cc = t & 3;
        float s = pw[0][qq][cc] + pw[1][qq][cc] + pw[2][qq][cc] + pw[3][qq][cc]
                + bv[0];
        const float att = 1.0f / (1.0f + expf(-s));
        const int hw = hw0 + t;
        const int h  = hw / W;
        const int w  = hw - h * W;
        const bool border = (h == 0) | (h == H - 1) | (w == 0) | (w == W - 1);
        comb[t] = att * (border ? 2.0f : 1.0f);
    }
    __syncthreads();

    // ---- scale registers and store, coalesced 16B stores ----
    const f32x4 m4 = *reinterpret_cast<const f32x4*>(&comb[q * 4]);
    #pragma unroll
    for (int k = 0; k < 16; ++k) {
        const int c = k * 16 + c0;
        f32x4 r = v[k] * m4;
        __builtin_nontemporal_store(r,
            reinterpret_cast<f32x4*>(ob + (size_t)c * HW + q * 4));
    }
}

extern "C" void kernel_launch(void* const* d_in, const int* in_sizes, int n_in,
                              void* d_out, int out_size, void* d_ws, size_t ws_size,
                              hipStream_t stream) {
    const float* x  = (const float*)d_in[0];
    const float* wv = (const float*)d_in[1];
    const float* bv = (const float*)d_in[2];
    float* out = (float*)d_out;

    dim3 grid(BATCH * TILES_PER_B);   // 12544 blocks
    fused_sigmoid_border_scale<<<grid, THREADS, 0, stream>>>(x, wv, bv, out);
}